// Round 3
// baseline (240.058 us; speedup 1.0000x reference)
//
#include <hip/hip_runtime.h>
#include <cstdint>
#include <cstddef>

// DigitCapsule dynamic routing, fp32.
// x[256,1152,8], W[1152,10,16,8], out v[256,10,16].
// R2 design: lane = b4*16 + d. The d-reduction (logits, squash-norm) is a
// 16-lane in-row DPP butterfly -> NO LDS, NO barriers anywhere.
// vsum trick: logits at round r = votes . (v0+...+v_{r-1}).
// Layouts: vsumT[J][B][D], spart[NCH][J][B][D] (d-minor, coalesced).
constexpr int Bn = 256, In = 1152, Pn = 8, Jn = 10, Dn = 16;
constexpr int CA = 12, NCH = In / CA;  // i-chunk, 96 chunks

template <int CTRL>
__device__ __forceinline__ float dpp_add(float v) {
  const int s =
      __builtin_amdgcn_update_dpp(0, __float_as_int(v), CTRL, 0xf, 0xf, true);
  return v + __int_as_float(s);
}

// Sum over the 16 lanes of each row (lane&15 = d); every lane gets the sum.
// quad_perm[1,0,3,2]=0xB1 (xor1), quad_perm[2,3,0,1]=0x4E (xor2),
// row_ror:4=0x124, row_ror:8=0x128.
__device__ __forceinline__ float rowsum16(float v) {
  v = dpp_add<0xB1>(v);
  v = dpp_add<0x4E>(v);
  v = dpp_add<0x124>(v);
  v = dpp_add<0x128>(v);
  return v;
}

// capsV: one routing round's weighted vote sum over an i-chunk.
// thread: d = t&15, b = blockIdx.y*16 + (t>>4). block = (chunk, b-group).
// Per i: vt[j] = W[i,j,d,:].x[b,i,:] (2 float4 loads each, contiguous),
// MODE 1: l[j] = rowsum16(vt[j]*vs[j]) -> softmax -> acc[j] += c[j]*vt[j].
// MODE 0: acc[j] += vt[j], scaled by c=0.1 at the end (softmax of zeros).
template <int MODE>
__global__ __launch_bounds__(256) void capsV(
    const float* __restrict__ x, const float* __restrict__ w,
    const float* __restrict__ vsumT, float* __restrict__ spart) {
  const int t = threadIdx.x;
  const int d = t & 15, bloc = t >> 4;
  const int ch = blockIdx.x, b = blockIdx.y * 16 + bloc;

  float vs[Jn], acc[Jn];
  #pragma unroll
  for (int j = 0; j < Jn; ++j) {
    acc[j] = 0.f;
    if (MODE) vs[j] = vsumT[((size_t)j * Bn + b) * Dn + d];
  }

  const int i0 = ch * CA;
  for (int ii = 0; ii < CA; ++ii) {
    const int i = i0 + ii;
    const float4* xp =
        reinterpret_cast<const float4*>(x + ((size_t)b * In + i) * Pn);
    const float4 x0 = xp[0], x1 = xp[1];

    float vt[Jn];
    #pragma unroll
    for (int j = 0; j < Jn; ++j) {
      const float4* wp = reinterpret_cast<const float4*>(
          w + (((size_t)i * Jn + j) * Dn + d) * Pn);
      const float4 w0 = wp[0], w1 = wp[1];
      float dot = w0.x * x0.x;
      dot = fmaf(w0.y, x0.y, dot); dot = fmaf(w0.z, x0.z, dot);
      dot = fmaf(w0.w, x0.w, dot);
      dot = fmaf(w1.x, x1.x, dot); dot = fmaf(w1.y, x1.y, dot);
      dot = fmaf(w1.z, x1.z, dot); dot = fmaf(w1.w, x1.w, dot);
      vt[j] = dot;
    }

    if (MODE) {
      float l[Jn];
      #pragma unroll
      for (int j = 0; j < Jn; ++j) l[j] = rowsum16(vt[j] * vs[j]);
      float m = l[0];
      #pragma unroll
      for (int j = 1; j < Jn; ++j) m = fmaxf(m, l[j]);
      float ssum = 0.f;
      #pragma unroll
      for (int j = 0; j < Jn; ++j) { l[j] = __expf(l[j] - m); ssum += l[j]; }
      const float inv = 1.f / ssum;
      #pragma unroll
      for (int j = 0; j < Jn; ++j) acc[j] = fmaf(l[j] * inv, vt[j], acc[j]);
    } else {
      #pragma unroll
      for (int j = 0; j < Jn; ++j) acc[j] += vt[j];
    }
  }

  const float cs = MODE ? 1.f : 0.1f;
  #pragma unroll
  for (int j = 0; j < Jn; ++j)
    spart[(((size_t)ch * Jn + j) * Bn + b) * Dn + d] = acc[j] * cs;
}

// capsF: reduce 96 chunk-partials, squash. No LDS: n2 via rowsum16.
// thread: d = t&15, b = blockIdx.y*16 + (t>>4). block = (j, b-group).
// MODE 0: vsumT = v ; MODE 1: vsumT += v ; MODE 2: out[b][j][d] = v.
template <int MODE>
__global__ __launch_bounds__(256) void capsF(
    const float* __restrict__ spart, float* __restrict__ vsumT,
    float* __restrict__ out) {
  const int t = threadIdx.x;
  const int d = t & 15, bloc = t >> 4;
  const int j = blockIdx.x, b = blockIdx.y * 16 + bloc;

  const size_t cstride = (size_t)Jn * Bn * Dn;  // chunk stride in floats
  const float* sp = spart + ((size_t)j * Bn + b) * Dn + d;
  float s0 = 0.f, s1 = 0.f;
  #pragma unroll 4
  for (int ch = 0; ch < NCH; ch += 2) {
    s0 += sp[0];
    s1 += sp[cstride];
    sp += 2 * cstride;
  }
  const float z = s0 + s1;
  const float n2 = rowsum16(z * z);
  const float sc = n2 / (1.f + n2) / sqrtf(n2 + 1e-7f);
  const float v = z * sc;
  if (MODE == 2) {
    out[((size_t)b * Jn + j) * Dn + d] = v;
  } else if (MODE == 1) {
    vsumT[((size_t)j * Bn + b) * Dn + d] += v;
  } else {
    vsumT[((size_t)j * Bn + b) * Dn + d] = v;
  }
}

extern "C" void kernel_launch(void* const* d_in, const int* in_sizes, int n_in,
                              void* d_out, int out_size, void* d_ws, size_t ws_size,
                              hipStream_t stream) {
  const float* x = (const float*)d_in[0];  // [256,1152,8]
  const float* w = (const float*)d_in[1];  // [1152,10,16,8]
  float* vsumT = (float*)d_ws;                      // [J][B][D]  0.16 MB
  float* spart = vsumT + (size_t)Jn * Bn * Dn;      // [NCH][J][B][D] 15.73 MB
  float* out = (float*)d_out;                       // [256,10,16]

  const dim3 gV(NCH, Bn / 16), gF(Jn, Bn / 16);

  capsV<0><<<gV, 256, 0, stream>>>(x, w, nullptr, spart);
  capsF<0><<<gF, 256, 0, stream>>>(spart, vsumT, out);   // vsum = v0

  capsV<1><<<gV, 256, 0, stream>>>(x, w, vsumT, spart);  // round 1
  capsF<1><<<gF, 256, 0, stream>>>(spart, vsumT, out);   // vsum += v1

  capsV<1><<<gV, 256, 0, stream>>>(x, w, vsumT, spart);  // round 2
  capsF<2><<<gF, 256, 0, stream>>>(spart, vsumT, out);   // out = v2
}

// Round 4
// 239.612 us; speedup vs baseline: 1.0019x; 1.0019x over previous
//
#include <hip/hip_runtime.h>
#include <cstdint>
#include <cstddef>

// DigitCapsule dynamic routing, fp32.
// x[256,1152,8], W[1152,10,16,8], out v[256,10,16].
// Design: lane = b4*16 + d. d-reductions (logits, squash-norm) are 16-lane
// xor-butterflies on the LDS pipe (ds_swizzle) -> no barriers, no shared mem.
// vsum trick: logits at round r = votes . (v0+...+v_{r-1}).
// R4: __launch_bounds__(256,3) + full W-load hoist (20 float4 in flight) to
// fix the VGPR-starved latency binding seen in R3 (VGPR=56, VALUBusy 47%).
constexpr int Bn = 256, In = 1152, Pn = 8, Jn = 10, Dn = 16;
constexpr int CA = 24, NCH = In / CA;  // i-chunk, 48 chunks

template <int MASK>
__device__ __forceinline__ float swzadd(float v) {
  const int s = __builtin_amdgcn_ds_swizzle(__float_as_int(v), MASK);
  return v + __int_as_float(s);
}

// Sum over the 16 lanes of each row (lane&15 = d); every lane gets the sum.
// ds_swizzle BitMode: offset = xor<<10 | or<<5 | and(0x1F). LDS-pipe, no VALU
// data movement, no hazards, stays within 16-lane groups for xor<16.
__device__ __forceinline__ float rowsum16(float v) {
  v = swzadd<0x041F>(v);  // xor 1
  v = swzadd<0x081F>(v);  // xor 2
  v = swzadd<0x101F>(v);  // xor 4
  v = swzadd<0x201F>(v);  // xor 8
  return v;
}

__device__ __forceinline__ float dot8(const float4 a0, const float4 a1,
                                      const float4 b0, const float4 b1) {
  float s = a0.x * b0.x;
  s = fmaf(a0.y, b0.y, s); s = fmaf(a0.z, b0.z, s); s = fmaf(a0.w, b0.w, s);
  s = fmaf(a1.x, b1.x, s); s = fmaf(a1.y, b1.y, s); s = fmaf(a1.z, b1.z, s);
  s = fmaf(a1.w, b1.w, s);
  return s;
}

// capsV: one routing round's weighted vote sum over an i-chunk.
// thread: d = t&15, b = blockIdx.y*16 + (t>>4). block = (chunk, b-group).
// Per i: hoist ALL W[i,j,d,:] (20 float4) + x (2 float4) into registers,
// then votes vt[j], logits via rowsum16, softmax (no max-sub: logits ~1e-1),
// acc[j] += c[j]*vt[j].
// MODE 0: acc[j] += vt[j], scaled by 0.1 at the end (softmax of zeros).
template <int MODE>
__global__ __launch_bounds__(256, 3) void capsV(
    const float* __restrict__ x, const float* __restrict__ w,
    const float* __restrict__ vsumT, float* __restrict__ spart) {
  const int t = threadIdx.x;
  const int d = t & 15, bloc = t >> 4;
  const int ch = blockIdx.x, b = blockIdx.y * 16 + bloc;

  float vs[Jn], acc[Jn];
  #pragma unroll
  for (int j = 0; j < Jn; ++j) {
    acc[j] = 0.f;
    if (MODE) vs[j] = vsumT[((size_t)j * Bn + b) * Dn + d];
  }

  const int i0 = ch * CA;
  for (int ii = 0; ii < CA; ++ii) {
    const int i = i0 + ii;
    const float4* xp =
        reinterpret_cast<const float4*>(x + ((size_t)b * In + i) * Pn);
    const float4 x0 = xp[0], x1 = xp[1];

    // Hoist all W loads for this i: 20 dwordx4 in flight at once.
    float4 wv0[Jn], wv1[Jn];
    const float* wi = w + (((size_t)i * Jn) * Dn + d) * Pn;
    #pragma unroll
    for (int j = 0; j < Jn; ++j) {
      const float4* wp =
          reinterpret_cast<const float4*>(wi + (size_t)j * Dn * Pn);
      wv0[j] = wp[0];
      wv1[j] = wp[1];
    }

    float vt[Jn];
    #pragma unroll
    for (int j = 0; j < Jn; ++j) vt[j] = dot8(wv0[j], wv1[j], x0, x1);

    if (MODE) {
      float l[Jn];
      #pragma unroll
      for (int j = 0; j < Jn; ++j) l[j] = rowsum16(vt[j] * vs[j]);
      // softmax over j; logits are O(0.1) so no max-subtraction needed.
      float ssum = 0.f;
      #pragma unroll
      for (int j = 0; j < Jn; ++j) { l[j] = __expf(l[j]); ssum += l[j]; }
      const float inv = __builtin_amdgcn_rcpf(ssum);
      #pragma unroll
      for (int j = 0; j < Jn; ++j) acc[j] = fmaf(l[j] * inv, vt[j], acc[j]);
    } else {
      #pragma unroll
      for (int j = 0; j < Jn; ++j) acc[j] += vt[j];
    }
  }

  const float cs = MODE ? 1.f : 0.1f;
  #pragma unroll
  for (int j = 0; j < Jn; ++j)
    spart[(((size_t)ch * Jn + j) * Bn + b) * Dn + d] = acc[j] * cs;
}

// capsF: reduce 48 chunk-partials, squash. No LDS tiles: n2 via rowsum16.
// thread: d = t&15, b = blockIdx.y*16 + (t>>4). block = (j, b-group).
// MODE 0: vsumT = v ; MODE 1: vsumT += v ; MODE 2: out[b][j][d] = v.
template <int MODE>
__global__ __launch_bounds__(256) void capsF(
    const float* __restrict__ spart, float* __restrict__ vsumT,
    float* __restrict__ out) {
  const int t = threadIdx.x;
  const int d = t & 15, bloc = t >> 4;
  const int j = blockIdx.x, b = blockIdx.y * 16 + bloc;

  const size_t cstride = (size_t)Jn * Bn * Dn;  // chunk stride in floats
  const float* sp = spart + ((size_t)j * Bn + b) * Dn + d;
  float s0 = 0.f, s1 = 0.f;
  #pragma unroll 4
  for (int ch = 0; ch < NCH; ch += 2) {
    s0 += sp[0];
    s1 += sp[cstride];
    sp += 2 * cstride;
  }
  const float z = s0 + s1;
  const float n2 = rowsum16(z * z);
  const float sc = n2 / (1.f + n2) / sqrtf(n2 + 1e-7f);
  const float v = z * sc;
  if (MODE == 2) {
    out[((size_t)b * Jn + j) * Dn + d] = v;
  } else if (MODE == 1) {
    vsumT[((size_t)j * Bn + b) * Dn + d] += v;
  } else {
    vsumT[((size_t)j * Bn + b) * Dn + d] = v;
  }
}

extern "C" void kernel_launch(void* const* d_in, const int* in_sizes, int n_in,
                              void* d_out, int out_size, void* d_ws, size_t ws_size,
                              hipStream_t stream) {
  const float* x = (const float*)d_in[0];  // [256,1152,8]
  const float* w = (const float*)d_in[1];  // [1152,10,16,8]
  float* vsumT = (float*)d_ws;                      // [J][B][D]  0.16 MB
  float* spart = vsumT + (size_t)Jn * Bn * Dn;      // [NCH][J][B][D] 7.86 MB
  float* out = (float*)d_out;                       // [256,10,16]

  const dim3 gV(NCH, Bn / 16), gF(Jn, Bn / 16);

  capsV<0><<<gV, 256, 0, stream>>>(x, w, nullptr, spart);
  capsF<0><<<gF, 256, 0, stream>>>(spart, vsumT, out);   // vsum = v0

  capsV<1><<<gV, 256, 0, stream>>>(x, w, vsumT, spart);  // round 1
  capsF<1><<<gF, 256, 0, stream>>>(spart, vsumT, out);   // vsum += v1

  capsV<1><<<gV, 256, 0, stream>>>(x, w, vsumT, spart);  // round 2
  capsF<2><<<gF, 256, 0, stream>>>(spart, vsumT, out);   // out = v2
}

// Round 5
// 238.039 us; speedup vs baseline: 1.0085x; 1.0066x over previous
//
#include <hip/hip_runtime.h>
#include <cstdint>
#include <cstddef>

// DigitCapsule dynamic routing, fp32.
// x[256,1152,8], W[1152,10,16,8], out v[256,10,16].
// Design: lane = g*16 + d (16 d-lanes per b). d-reductions (logits, squash)
// are 16-lane xor-butterflies via ds_swizzle -> no barriers in capsV.
// vsum trick: logits at round r = votes . (v0+...+v_{r-1}).
// R5: force the W-load cluster the compiler refused in R3/R4:
//   - amdgpu_waves_per_eu(2,3): cap occupancy target -> ~170 VGPR budget,
//     scheduler stops sinking loads to chase 8 waves/EU.
//   - sched_barrier(0) after the 22-load cluster: loads must issue before
//     any FMA -> one vmcnt drain per i, ~22 loads in flight per wave.
//   - CA=6 (192 chunks, 3072 blocks) restores grid TLP lost at CA=24.
constexpr int Bn = 256, In = 1152, Pn = 8, Jn = 10, Dn = 16;
constexpr int CA = 6, NCH = In / CA;  // 192 chunks

template <int MASK>
__device__ __forceinline__ float swzadd(float v) {
  const int s = __builtin_amdgcn_ds_swizzle(__float_as_int(v), MASK);
  return v + __int_as_float(s);
}

// Sum over the 16 lanes of each row (lane&15 = d); every lane gets the sum.
// ds_swizzle BitMode: offset = xor<<10 | or<<5 | and(0x1F).
__device__ __forceinline__ float rowsum16(float v) {
  v = swzadd<0x041F>(v);  // xor 1
  v = swzadd<0x081F>(v);  // xor 2
  v = swzadd<0x101F>(v);  // xor 4
  v = swzadd<0x201F>(v);  // xor 8
  return v;
}

__device__ __forceinline__ float dot8(const float4 a0, const float4 a1,
                                      const float4 b0, const float4 b1) {
  float s = a0.x * b0.x;
  s = fmaf(a0.y, b0.y, s); s = fmaf(a0.z, b0.z, s); s = fmaf(a0.w, b0.w, s);
  s = fmaf(a1.x, b1.x, s); s = fmaf(a1.y, b1.y, s); s = fmaf(a1.z, b1.z, s);
  s = fmaf(a1.w, b1.w, s);
  return s;
}

// capsV: one routing round's weighted vote sum over an i-chunk.
// thread: d = t&15, b = blockIdx.y*16 + (t>>4). block = (chunk, b-group).
// Per i: cluster-load ALL of W[i,*,d,:] (20 float4) + x (2 float4), hard
// sched fence, then 80 FMAs + logits (rowsum16) + softmax + acc.
// MODE 0: softmax of zero logits = 0.1 exactly -> acc of raw votes * 0.1.
template <int MODE>
__global__ __launch_bounds__(256)
__attribute__((amdgpu_waves_per_eu(2, 3)))
void capsV(const float* __restrict__ x, const float* __restrict__ w,
           const float* __restrict__ vsumT, float* __restrict__ spart) {
  const int t = threadIdx.x;
  const int d = t & 15, g = t >> 4;
  const int ch = blockIdx.x, b = blockIdx.y * 16 + g;

  float vs[Jn], acc[Jn];
  #pragma unroll
  for (int j = 0; j < Jn; ++j) {
    acc[j] = 0.f;
    if (MODE) vs[j] = vsumT[((size_t)j * Bn + b) * Dn + d];
  }

  const int i0 = ch * CA;
  const float* xp = x + ((size_t)b * In + i0) * Pn;
  const float* wp = w + (((size_t)i0 * Jn) * Dn + d) * Pn;

  for (int ii = 0; ii < CA; ++ii) {
    // ---- load cluster: 2 + 20 dwordx4, all issued before any math ----
    const float4 x0 = reinterpret_cast<const float4*>(xp)[0];
    const float4 x1 = reinterpret_cast<const float4*>(xp)[1];
    float4 wv0[Jn], wv1[Jn];
    #pragma unroll
    for (int j = 0; j < Jn; ++j) {
      const float4* wj =
          reinterpret_cast<const float4*>(wp + (size_t)j * (Dn * Pn));
      wv0[j] = wj[0];
      wv1[j] = wj[1];
    }
    __builtin_amdgcn_sched_barrier(0);  // fence: no FMA scheduled above

    float vt[Jn];
    #pragma unroll
    for (int j = 0; j < Jn; ++j) vt[j] = dot8(wv0[j], wv1[j], x0, x1);

    if (MODE) {
      float l[Jn];
      #pragma unroll
      for (int j = 0; j < Jn; ++j) l[j] = rowsum16(vt[j] * vs[j]);
      // softmax over j; logits are O(0.1) so no max-subtraction needed.
      float ssum = 0.f;
      #pragma unroll
      for (int j = 0; j < Jn; ++j) { l[j] = __expf(l[j]); ssum += l[j]; }
      const float inv = __builtin_amdgcn_rcpf(ssum);
      #pragma unroll
      for (int j = 0; j < Jn; ++j) acc[j] = fmaf(l[j] * inv, vt[j], acc[j]);
    } else {
      #pragma unroll
      for (int j = 0; j < Jn; ++j) acc[j] += vt[j];
    }

    xp += Pn;
    wp += (size_t)Jn * Dn * Pn;
  }

  const float cs = MODE ? 1.f : 0.1f;
  #pragma unroll
  for (int j = 0; j < Jn; ++j)
    spart[(((size_t)ch * Jn + j) * Bn + b) * Dn + d] = acc[j] * cs;
}

// capsF: reduce 192 chunk-partials, squash. 1024 threads: 4 chunk-groups
// (cg = t>>8) each privately sum 48 chunks; LDS combine across cg; squash
// norm via rowsum16 in the t<256 tail. block = (j, b-group of 16).
// MODE 0: vsumT = v ; MODE 1: vsumT += v ; MODE 2: out[b][j][d] = v.
template <int MODE>
__global__ __launch_bounds__(1024) void capsF(
    const float* __restrict__ spart, float* __restrict__ vsumT,
    float* __restrict__ out) {
  __shared__ float red[4][16][16];
  const int t = threadIdx.x;
  const int cg = t >> 8, r = t & 255, g = r >> 4, d = r & 15;
  const int j = blockIdx.x, b = blockIdx.y * 16 + g;

  const size_t cstride = (size_t)Jn * Bn * Dn;  // one chunk, in floats
  const size_t cstep = 4 * cstride;             // stride between my chunks
  const float* sp = spart + (((size_t)cg * Jn + j) * Bn + b) * Dn + d;
  float s0 = 0.f, s1 = 0.f;
  #pragma unroll 4
  for (int k = 0; k < NCH / 4; k += 2) {
    s0 += sp[0];
    s1 += sp[cstep];
    sp += 2 * cstep;
  }
  red[cg][g][d] = s0 + s1;
  __syncthreads();
  if (t < 256) {
    const float z = red[0][g][d] + red[1][g][d] + red[2][g][d] + red[3][g][d];
    const float n2 = rowsum16(z * z);
    const float sc = n2 / (1.f + n2) / sqrtf(n2 + 1e-7f);
    const float v = z * sc;
    if (MODE == 2) {
      out[((size_t)b * Jn + j) * Dn + d] = v;
    } else if (MODE == 1) {
      vsumT[((size_t)j * Bn + b) * Dn + d] += v;
    } else {
      vsumT[((size_t)j * Bn + b) * Dn + d] = v;
    }
  }
}

extern "C" void kernel_launch(void* const* d_in, const int* in_sizes, int n_in,
                              void* d_out, int out_size, void* d_ws, size_t ws_size,
                              hipStream_t stream) {
  const float* x = (const float*)d_in[0];  // [256,1152,8]
  const float* w = (const float*)d_in[1];  // [1152,10,16,8]
  float* vsumT = (float*)d_ws;                      // [J][B][D]   0.16 MB
  float* spart = vsumT + (size_t)Jn * Bn * Dn;      // [NCH][J][B][D] 31.5 MB
  float* out = (float*)d_out;                       // [256,10,16]

  const dim3 gV(NCH, Bn / 16), gF(Jn, Bn / 16);

  capsV<0><<<gV, 256, 0, stream>>>(x, w, nullptr, spart);
  capsF<0><<<gF, 1024, 0, stream>>>(spart, vsumT, out);   // vsum = v0

  capsV<1><<<gV, 256, 0, stream>>>(x, w, vsumT, spart);   // round 1
  capsF<1><<<gF, 1024, 0, stream>>>(spart, vsumT, out);   // vsum += v1

  capsV<1><<<gV, 256, 0, stream>>>(x, w, vsumT, spart);   // round 2
  capsF<2><<<gF, 1024, 0, stream>>>(spart, vsumT, out);   // out = v2
}

// Round 6
// 182.510 us; speedup vs baseline: 1.3153x; 1.3043x over previous
//
#include <hip/hip_runtime.h>
#include <cstdint>
#include <cstddef>

// DigitCapsule dynamic routing, fp32.
// x[256,1152,8], W[1152,10,16,8], out v[256,10,16].
// Design: lane = q*16 + d. d-reductions (logits, squash) are 16-lane
// xor-butterflies via ds_swizzle -> no barriers in capsV.
// vsum trick: logits at round r = votes . (v0+...+v_{r-1}).
// R6: each thread serves TWO b's (b0 = base+q, b1 = b0+16). W[i,j,d,:] is
// b-independent -> one W load now feeds 16 FMAs (2 dots) instead of 8,
// doubling the FMA:load ratio that R3-R5 showed to be the latency binding.
// amdgpu_waves_per_eu(3,4): ~120-VGPR budget -> 4 waves/SIMD if it fits.
constexpr int Bn = 256, In = 1152, Pn = 8, Jn = 10, Dn = 16;
constexpr int CA = 12, NCH = In / CA;  // 96 chunks

template <int MASK>
__device__ __forceinline__ float swzadd(float v) {
  const int s = __builtin_amdgcn_ds_swizzle(__float_as_int(v), MASK);
  return v + __int_as_float(s);
}

// Sum over the 16 lanes of each row (lane&15 = d); every lane gets the sum.
// ds_swizzle BitMode: offset = xor<<10 | or<<5 | and(0x1F). LDS pipe.
__device__ __forceinline__ float rowsum16(float v) {
  v = swzadd<0x041F>(v);  // xor 1
  v = swzadd<0x081F>(v);  // xor 2
  v = swzadd<0x101F>(v);  // xor 4
  v = swzadd<0x201F>(v);  // xor 8
  return v;
}

__device__ __forceinline__ float dot8(const float4 a0, const float4 a1,
                                      const float4 b0, const float4 b1) {
  float s = a0.x * b0.x;
  s = fmaf(a0.y, b0.y, s); s = fmaf(a0.z, b0.z, s); s = fmaf(a0.w, b0.w, s);
  s = fmaf(a1.x, b1.x, s); s = fmaf(a1.y, b1.y, s); s = fmaf(a1.z, b1.z, s);
  s = fmaf(a1.w, b1.w, s);
  return s;
}

// capsV: one routing round's weighted vote sum over an i-chunk, 2 b's/thread.
// thread: d = t&15, q = t>>4; b0 = blockIdx.y*32 + q, b1 = b0 + 16.
// block = (chunk, b-group of 32). Per (i,j): one 32B W load -> two dots.
// MODE 0: softmax of zero logits = 0.1 exactly -> raw vote sum * 0.1.
template <int MODE>
__global__ __launch_bounds__(256)
__attribute__((amdgpu_waves_per_eu(3, 4)))
void capsV(const float* __restrict__ x, const float* __restrict__ w,
           const float* __restrict__ vsumT, float* __restrict__ spart) {
  const int t = threadIdx.x;
  const int d = t & 15, q = t >> 4;
  const int ch = blockIdx.x;
  const int b0 = blockIdx.y * 32 + q, b1 = b0 + 16;

  float vs0[Jn], vs1[Jn], acc0[Jn], acc1[Jn];
  #pragma unroll
  for (int j = 0; j < Jn; ++j) {
    acc0[j] = 0.f; acc1[j] = 0.f;
    if (MODE) {
      vs0[j] = vsumT[((size_t)j * Bn + b0) * Dn + d];
      vs1[j] = vsumT[((size_t)j * Bn + b1) * Dn + d];
    }
  }

  const int i0 = ch * CA;
  const float* xp0 = x + ((size_t)b0 * In + i0) * Pn;
  const float* xp1 = x + ((size_t)b1 * In + i0) * Pn;
  const float* wp = w + (((size_t)i0 * Jn) * Dn + d) * Pn;

  for (int ii = 0; ii < CA; ++ii) {
    const float4 xa0 = reinterpret_cast<const float4*>(xp0)[0];
    const float4 xa1 = reinterpret_cast<const float4*>(xp0)[1];
    const float4 xb0 = reinterpret_cast<const float4*>(xp1)[0];
    const float4 xb1 = reinterpret_cast<const float4*>(xp1)[1];

    float vt0[Jn], vt1[Jn];
    #pragma unroll
    for (int j = 0; j < Jn; ++j) {
      const float4* wj =
          reinterpret_cast<const float4*>(wp + (size_t)j * (Dn * Pn));
      const float4 w0 = wj[0], w1 = wj[1];
      vt0[j] = dot8(w0, w1, xa0, xa1);
      vt1[j] = dot8(w0, w1, xb0, xb1);
    }

    if (MODE) {
      float l0[Jn], l1[Jn];
      #pragma unroll
      for (int j = 0; j < Jn; ++j) {
        l0[j] = rowsum16(vt0[j] * vs0[j]);
        l1[j] = rowsum16(vt1[j] * vs1[j]);
      }
      // softmax over j; logits are O(0.1) so no max-subtraction needed.
      float sa = 0.f, sb = 0.f;
      #pragma unroll
      for (int j = 0; j < Jn; ++j) {
        l0[j] = __expf(l0[j]); sa += l0[j];
        l1[j] = __expf(l1[j]); sb += l1[j];
      }
      const float ia = __builtin_amdgcn_rcpf(sa);
      const float ib = __builtin_amdgcn_rcpf(sb);
      #pragma unroll
      for (int j = 0; j < Jn; ++j) {
        acc0[j] = fmaf(l0[j] * ia, vt0[j], acc0[j]);
        acc1[j] = fmaf(l1[j] * ib, vt1[j], acc1[j]);
      }
    } else {
      #pragma unroll
      for (int j = 0; j < Jn; ++j) { acc0[j] += vt0[j]; acc1[j] += vt1[j]; }
    }

    xp0 += Pn;
    xp1 += Pn;
    wp += (size_t)Jn * Dn * Pn;
  }

  const float cs = MODE ? 1.f : 0.1f;
  #pragma unroll
  for (int j = 0; j < Jn; ++j) {
    spart[(((size_t)ch * Jn + j) * Bn + b0) * Dn + d] = acc0[j] * cs;
    spart[(((size_t)ch * Jn + j) * Bn + b1) * Dn + d] = acc1[j] * cs;
  }
}

// capsF: reduce 96 chunk-partials, squash. 1024 threads: 4 chunk-groups
// (cg = t>>8) each privately sum 24 chunks; LDS combine across cg; squash
// norm via rowsum16 in the t<256 tail. block = (j, b-group of 16).
// MODE 0: vsumT = v ; MODE 1: vsumT += v ; MODE 2: out[b][j][d] = v.
template <int MODE>
__global__ __launch_bounds__(1024) void capsF(
    const float* __restrict__ spart, float* __restrict__ vsumT,
    float* __restrict__ out) {
  __shared__ float red[4][16][16];
  const int t = threadIdx.x;
  const int cg = t >> 8, r = t & 255, g = r >> 4, d = r & 15;
  const int j = blockIdx.x, b = blockIdx.y * 16 + g;

  const size_t cstride = (size_t)Jn * Bn * Dn;  // one chunk, in floats
  const size_t cstep = 4 * cstride;             // stride between my chunks
  const float* sp = spart + (((size_t)cg * Jn + j) * Bn + b) * Dn + d;
  float s0 = 0.f, s1 = 0.f;
  #pragma unroll 4
  for (int k = 0; k < NCH / 4; k += 2) {
    s0 += sp[0];
    s1 += sp[cstep];
    sp += 2 * cstep;
  }
  red[cg][g][d] = s0 + s1;
  __syncthreads();
  if (t < 256) {
    const float z = red[0][g][d] + red[1][g][d] + red[2][g][d] + red[3][g][d];
    const float n2 = rowsum16(z * z);
    const float sc = n2 / (1.f + n2) / sqrtf(n2 + 1e-7f);
    const float v = z * sc;
    if (MODE == 2) {
      out[((size_t)b * Jn + j) * Dn + d] = v;
    } else if (MODE == 1) {
      vsumT[((size_t)j * Bn + b) * Dn + d] += v;
    } else {
      vsumT[((size_t)j * Bn + b) * Dn + d] = v;
    }
  }
}

extern "C" void kernel_launch(void* const* d_in, const int* in_sizes, int n_in,
                              void* d_out, int out_size, void* d_ws, size_t ws_size,
                              hipStream_t stream) {
  const float* x = (const float*)d_in[0];  // [256,1152,8]
  const float* w = (const float*)d_in[1];  // [1152,10,16,8]
  float* vsumT = (float*)d_ws;                      // [J][B][D]   0.16 MB
  float* spart = vsumT + (size_t)Jn * Bn * Dn;      // [NCH][J][B][D] 15.7 MB
  float* out = (float*)d_out;                       // [256,10,16]

  const dim3 gV(NCH, Bn / 32), gF(Jn, Bn / 16);

  capsV<0><<<gV, 256, 0, stream>>>(x, w, nullptr, spart);
  capsF<0><<<gF, 1024, 0, stream>>>(spart, vsumT, out);   // vsum = v0

  capsV<1><<<gV, 256, 0, stream>>>(x, w, vsumT, spart);   // round 1
  capsF<1><<<gF, 1024, 0, stream>>>(spart, vsumT, out);   // vsum += v1

  capsV<1><<<gV, 256, 0, stream>>>(x, w, vsumT, spart);   // round 2
  capsF<2><<<gF, 1024, 0, stream>>>(spart, vsumT, out);   // out = v2
}